// Round 7
// baseline (338.853 us; speedup 1.0000x reference)
//
#include <hip/hip_runtime.h>
#include <math.h>

#define NNODES 10000
#define NEDGES 100000

// ---------------- compile-time Clebsch-Gordan (port of reference) ----------------
struct Cplx { double re, im; };

constexpr double cfact(int n){ double r=1.0; for(int i=2;i<=n;++i) r*=i; return r; }

constexpr double csqrt_(double x){
  if (x<=0.0) return 0.0;
  double g = x<1.0 ? 1.0 : x;
  for (int it=0; it<64; ++it){ double ng = 0.5*(g + x/g); if (ng==g) break; g = ng; }
  return g;
}

constexpr double cg_coeff(int j1,int m1,int j2,int m2,int j3,int m3){
  if (m1+m2!=m3) return 0.0;
  int lo = j1>j2 ? j1-j2 : j2-j1;
  if (j3<lo || j3>j1+j2) return 0.0;
  if (m1<-j1||m1>j1||m2<-j2||m2>j2||m3<-j3||m3>j3) return 0.0;
  double pre = csqrt_((2.0*j3+1.0)*cfact(j1+j2-j3)*cfact(j1-j2+j3)*cfact(-j1+j2+j3)/cfact(j1+j2+j3+1));
  pre *= csqrt_(cfact(j1+m1)*cfact(j1-m1)*cfact(j2+m2)*cfact(j2-m2)*cfact(j3+m3)*cfact(j3-m3));
  double s = 0.0;
  for (int k=0;k<=j1+j2+j3;++k){
    int d0=j1+j2-j3-k, d1=j1-m1-k, d2=j2+m2-k, d3=j3-j2+m1+k, d4=j3-j1-m2+k;
    if (d0<0||d1<0||d2<0||d3<0||d4<0) continue;
    double term = 1.0/(cfact(k)*cfact(d0)*cfact(d1)*cfact(d2)*cfact(d3)*cfact(d4));
    s += (k&1) ? -term : term;
  }
  return pre*s;
}

constexpr Cplx uent(int l,int a,int i){
  const double s = 0.70710678118654752440;
  int ma = a - l;
  if (ma==0) { if (i==l) return Cplx{1.0,0.0}; return Cplx{0.0,0.0}; }
  if (ma>0){
    int m = ma; double sg = (m&1) ? -1.0 : 1.0;
    if (i==l+m) return Cplx{sg*s, 0.0};
    if (i==l-m) return Cplx{s, 0.0};
    return Cplx{0.0,0.0};
  }
  int m = -ma; double sg = (m&1) ? -1.0 : 1.0;
  if (i==l+m) return Cplx{0.0, -sg*s};
  if (i==l-m) return Cplx{0.0, s};
  return Cplx{0.0,0.0};
}

constexpr double real_cg_entry(int l1,int l2,int l3,int a,int b,int c){
  double acc = 0.0;
  int ii0 = a, ii1 = 2*l1-a;
  int jj0 = b, jj1 = 2*l2-b;
  for (int x=0;x<2;++x){
    int i = (x==0)? ii0 : ii1;
    if (x==1 && ii1==ii0) break;
    Cplx u1 = uent(l1,a,i); if (u1.re==0.0 && u1.im==0.0) continue;
    for (int y=0;y<2;++y){
      int j = (y==0)? jj0 : jj1;
      if (y==1 && jj1==jj0) break;
      Cplx u2 = uent(l2,b,j); if (u2.re==0.0 && u2.im==0.0) continue;
      int k = (i-l1)+(j-l2)+l3;
      if (k<0 || k>2*l3) continue;
      Cplx u3 = uent(l3,c,k); if (u3.re==0.0 && u3.im==0.0) continue;
      double cg = cg_coeff(l1,i-l1,l2,j-l2,l3,k-l3);
      if (cg==0.0) continue;
      double pr = u1.re*u2.re - u1.im*u2.im;
      double pi = u1.re*u2.im + u1.im*u2.re;
      acc += (pr*u3.re + pi*u3.im) * cg;
    }
  }
  return acc;
}

struct CGT { float v[5][5][5]; };
constexpr CGT make_cg(int l1,int l2,int l3){
  CGT t{};
  for (int a=0;a<2*l1+1;++a)
    for (int b=0;b<2*l2+1;++b)
      for (int c=0;c<2*l3+1;++c)
        t.v[a][b][c] = (float)real_cg_entry(l1,l2,l3,a,b,c);
  return t;
}

// ---------------- device helpers ----------------
__device__ __forceinline__ float silu_(float x){ return x / (1.0f + __expf(-x)); }

union H16 { _Float16 h; unsigned short u; };
__device__ __forceinline__ unsigned short f2h(float x){ H16 c; c.h = (_Float16)x; return c.u; }
__device__ __forceinline__ float h2f(unsigned short u){ H16 c; c.u = u; return (float)c.h; }

template<int L1,int L2,int L3>
__device__ __forceinline__ void tp_accum(const float* sp, const float* g, float rl, float* msg){
  constexpr CGT T = make_cg(L1,L2,L3);
  constexpr int NA = 2*L1+1, NB = 2*L2+1, ND = 2*L3+1;
  float t[ND];
#pragma unroll
  for (int d=0; d<ND; ++d) t[d] = 0.f;
#pragma unroll
  for (int b=0;b<NB;++b){
#pragma unroll
    for (int d=0; d<ND; ++d){
      float u = 0.f; bool any = false;
#pragma unroll
      for (int a=0;a<NA;++a){
        const float cg = T.v[a][b][d];
        if (cg != 0.f){ u = fmaf(cg, sp[a], u); any = true; }
      }
      if (any) t[d] = fmaf(u, g[b], t[d]);
    }
  }
#pragma unroll
  for (int d=0;d<ND;++d) msg[d] = fmaf(rl, t[d], msg[d]);
}

template<int L1,int L2,int L3>
__device__ __forceinline__ void sc_accum(const float* X, const float* Y, float w, float* out){
  constexpr CGT T = make_cg(L1,L2,L3);
  constexpr int NA = 2*L1+1, NB = 2*L2+1, ND = 2*L3+1;
#pragma unroll
  for (int d=0;d<ND;++d){
    float s = 0.f;
#pragma unroll
    for (int a=0;a<NA;++a){
#pragma unroll
      for (int b=0;b<NB;++b){
        const float cg = T.v[a][b][d];
        if (cg != 0.f) s = fmaf(cg*X[a], Y[b], s);
      }
    }
    out[d] = fmaf(w, s, out[d]);
  }
}

// ---------------- kernel 1: h1p (4-wave c-split per node); also zero deg ----------------
__global__ void __launch_bounds__(256) k_lin4(const float* __restrict__ h1,
                                              const float* __restrict__ W,
                                              float* __restrict__ h1p,
                                              int* __restrict__ deg){
  __shared__ float Pt[4][9][64];
  const int n = blockIdx.x;
  const int wid = threadIdx.x >> 6;
  const int lane = threadIdx.x & 63;
  const float* row = h1 + (long)n*576;
  float acc[9];
#pragma unroll
  for (int i=0;i<9;++i) acc[i] = 0.f;
  const int c0 = wid*16;
  for (int c=c0; c<c0+16; ++c){
    const float w0 = W[c*64 + lane];
    const float w1 = W[4096 + c*64 + lane];
    const float w2 = W[8192 + c*64 + lane];
    acc[0] = fmaf(row[c], w0, acc[0]);
#pragma unroll
    for (int m=0;m<3;++m) acc[1+m] = fmaf(row[64+m*64+c], w1, acc[1+m]);
#pragma unroll
    for (int m=0;m<5;++m) acc[4+m] = fmaf(row[256+m*64+c], w2, acc[4+m]);
  }
#pragma unroll
  for (int i=0;i<9;++i) Pt[wid][i][lane] = acc[i];
  if (threadIdx.x == 0) deg[n] = 0;
  __syncthreads();
  for (int idx = threadIdx.x; idx < 576; idx += 256){
    const int i = idx >> 6, c = idx & 63;
    h1p[(long)n*576 + idx] = (Pt[0][i][c]+Pt[1][i][c]+Pt[2][i][c]+Pt[3][i][c])*0.125f;
  }
}

// ---------------- kernel 1b: radial MLP hidden layers, lane = edge ----------------
__global__ void __launch_bounds__(256) k_mlp(const float* __restrict__ ele,
                                             const float* __restrict__ W0, const float* __restrict__ b0,
                                             const float* __restrict__ W1, const float* __restrict__ b1,
                                             const float* __restrict__ W2, const float* __restrict__ b2,
                                             float* __restrict__ hmlp){
  const int e = blockIdx.x*256 + threadIdx.x;
  if (e >= NEDGES) return;
  float x[8];
#pragma unroll
  for (int i=0;i<8;++i) x[i] = ele[(long)e*8 + i];
  float h[32];
#pragma unroll
  for (int d=0;d<32;++d){
    float acc = b0[d];
#pragma unroll
    for (int i=0;i<8;++i) acc = fmaf(x[i], W0[i*32+d], acc);
    h[d] = silu_(acc);
  }
#pragma unroll
  for (int L=0; L<2; ++L){
    const float* Wl = L ? W2 : W1;
    const float* bl = L ? b2 : b1;
    float acc[32];
#pragma unroll
    for (int d=0;d<32;++d) acc[d] = bl[d];
    for (int j=0;j<32;++j){
      const float hj = h[j];
#pragma unroll
      for (int d=0;d<32;++d) acc[d] = fmaf(hj, Wl[j*32+d], acc[d]);
    }
#pragma unroll
    for (int d=0;d<32;++d) h[d] += silu_(acc[d]);
  }
  float* o = hmlp + (long)e*32;
#pragma unroll
  for (int d=0;d<32;++d) o[d] = h[d];
}

// ---------------- CSR build kernels ----------------
__global__ void __launch_bounds__(256) k_hist(const int* __restrict__ receiver, int* __restrict__ deg){
  const int e = blockIdx.x*256 + threadIdx.x;
  if (e < NEDGES) atomicAdd(&deg[receiver[e]], 1);
}

__global__ void __launch_bounds__(256) k_scan(const int* __restrict__ deg,
                                              int* __restrict__ rowptr,
                                              int* __restrict__ cursor){
  __shared__ int sums[256];
  const int t = threadIdx.x;
  const int CH = 40;
  const int base = t*CH;
  int s = 0;
  for (int i=0;i<CH;++i){ int idx = base+i; if (idx < NNODES) s += deg[idx]; }
  sums[t] = s; __syncthreads();
  for (int off=1; off<256; off<<=1){
    int v = (t>=off) ? sums[t-off] : 0;
    __syncthreads();
    sums[t] += v;
    __syncthreads();
  }
  int run = (t==0) ? 0 : sums[t-1];
  for (int i=0;i<CH;++i){
    int idx = base+i;
    if (idx < NNODES){ rowptr[idx] = run; cursor[idx] = run; run += deg[idx]; }
  }
  if (t==255) rowptr[NNODES] = sums[255];
}

__global__ void __launch_bounds__(256) k_fill(const int* __restrict__ receiver,
                                              int* __restrict__ cursor,
                                              int* __restrict__ eidx){
  const int e = blockIdx.x*256 + threadIdx.x;
  if (e < NEDGES){
    int pos = atomicAdd(&cursor[receiver[e]], 1);
    eidx[pos] = e;
  }
}

// ---------------- kernel 2: per-l3-group edge kernels ----------------
// One kernel per l3 group: small live set by construction (g 36 + rl<=16 + w3v<=32),
// EPW=4 edges/wave, grid 6250 blocks x 3 kernels => 75K waves total (vs 12.5K before).
// g gathered before the rl-GEMM so the ~1000-cycle fma stretch hides its latency.
template<int G>
__global__ void __launch_bounds__(256, 4) k_edge_g(const int* __restrict__ sender,
                                             const float* __restrict__ hmlp,
                                             const float* __restrict__ sph,
                                             const float* __restrict__ h1p,
                                             const float* __restrict__ W3, const float* __restrict__ b3,
                                             unsigned short* __restrict__ msg16){
  constexpr int NP = (G==0) ? 3 : 4;
  constexpr int PIDS[3][4] = {{0,4,9,-1},{1,3,6,8},{2,5,7,10}};
  __shared__ float sps[4][36];
  const int wid  = threadIdx.x >> 6;
  const int lane = threadIdx.x & 63;
  const int ubase = __builtin_amdgcn_readfirstlane((blockIdx.x*4 + wid) * 4);

  if (lane < 36) sps[wid][lane] = sph[(long)ubase*9 + lane];

  int sidx[4];
#pragma unroll
  for (int e=0;e<4;++e) sidx[e] = sender[ubase+e];

  // gather sender features (latency hidden by the rl GEMM below)
  float g[4][9];
#pragma unroll
  for (int e=0;e<4;++e){
    const float* hp = h1p + (long)sidx[e]*576;
#pragma unroll
    for (int i=0;i<9;++i) g[e][i] = hp[i*64+lane];
  }

  const float* hu = hmlp + (long)ubase*32;   // wave-uniform -> s_load

  float rl[NP][4];
#pragma unroll
  for (int p=0;p<NP;++p){
    const float bb = b3[PIDS[G][p]*64 + lane];
#pragma unroll
    for (int e=0;e<4;++e) rl[p][e] = bb;
  }
  for (int jb=0;jb<32;jb+=8){
    float w3v[8][NP];
#pragma unroll
    for (int jj=0;jj<8;++jj)
#pragma unroll
      for (int p=0;p<NP;++p)
        w3v[jj][p] = W3[(jb+jj)*704 + PIDS[G][p]*64 + lane];
#pragma unroll
    for (int e=0;e<4;++e){
#pragma unroll
      for (int jj=0;jj<8;++jj){
        const float hj = hu[e*32 + jb + jj];
#pragma unroll
        for (int p=0;p<NP;++p) rl[p][e] = fmaf(hj, w3v[jj][p], rl[p][e]);
      }
    }
  }

#pragma unroll
  for (int e=0;e<4;++e){
    const float* sp = &sps[wid][e*9];
    const size_t mb = (size_t)(ubase+e)*576;
    if constexpr (G==0){
      float m0[1] = {0.f};
      tp_accum<0,0,0>(sp+0, &g[e][0], rl[0][e], m0);
      tp_accum<1,1,0>(sp+1, &g[e][1], rl[1][e], m0);
      tp_accum<2,2,0>(sp+4, &g[e][4], rl[2][e], m0);
      msg16[mb + lane] = f2h(m0[0]);
    } else if constexpr (G==1){
      float m1[3] = {0.f,0.f,0.f};
      tp_accum<0,1,1>(sp+0, &g[e][1], rl[0][e], m1);
      tp_accum<1,0,1>(sp+1, &g[e][0], rl[1][e], m1);
      tp_accum<1,2,1>(sp+1, &g[e][4], rl[2][e], m1);
      tp_accum<2,1,1>(sp+4, &g[e][1], rl[3][e], m1);
#pragma unroll
      for (int m=0;m<3;++m) msg16[mb + (1+m)*64 + lane] = f2h(m1[m]);
    } else {
      float m2[5] = {0.f,0.f,0.f,0.f,0.f};
      tp_accum<0,2,2>(sp+0, &g[e][4], rl[0][e], m2);
      tp_accum<1,1,2>(sp+1, &g[e][1], rl[1][e], m2);
      tp_accum<2,0,2>(sp+4, &g[e][0], rl[2][e], m2);
      tp_accum<2,2,2>(sp+4, &g[e][4], rl[3][e], m2);
#pragma unroll
      for (int m=0;m<5;++m) msg16[mb + (4+m)*64 + lane] = f2h(m2[m]);
    }
  }
}

// ---------------- kernel 3: node kernel, 4 waves per node ----------------
// Phase 1: waves gather-sum message quarters; Phase 3: Amix c-split; Phase 4:
// wave 0 does contraction; Phase 5: output GEMM c-split; partials reduced in LDS.
__global__ void __launch_bounds__(256) k_node4(const int* __restrict__ indices,
                                             const float* __restrict__ h1,
                                             const int* __restrict__ rowptr,
                                             const int* __restrict__ eidx,
                                             const unsigned short* __restrict__ msg16,
                                             const float* __restrict__ Wmix,
                                             const float* __restrict__ w1,
                                             const float* __restrict__ w2,
                                             const float* __restrict__ w3,
                                             const float* __restrict__ Wom,
                                             const float* __restrict__ Woh,
                                             float* __restrict__ out){
  __shared__ float Pt[4][9][64];
  __shared__ float Ash[9][64];
  __shared__ float Bsh[4][64];
  const int n = blockIdx.x;
  const int wid = threadIdx.x >> 6;
  const int lane = threadIdx.x & 63;
  const int e = indices[n];

  // phase 1: strided gather-sum of incoming messages
  {
    const int start = rowptr[n], end = rowptr[n+1];
    float pa[9];
#pragma unroll
    for (int i=0;i<9;++i) pa[i] = 0.f;
    for (int q = start + wid; q < end; q += 4){
      const int ed = eidx[q];
      const unsigned short* mp = msg16 + (size_t)ed*576;
#pragma unroll
      for (int i=0;i<9;++i) pa[i] += h2f(mp[i*64+lane]);
    }
#pragma unroll
    for (int i=0;i<9;++i) Pt[wid][i][lane] = pa[i];
  }
  __syncthreads();
  // phase 2: reduce to Ash
  for (int idx = threadIdx.x; idx < 576; idx += 256){
    const int i = idx >> 6, c = idx & 63;
    Ash[i][c] = Pt[0][i][c]+Pt[1][i][c]+Pt[2][i][c]+Pt[3][i][c];
  }
  __syncthreads();
  // phase 3: Amix partial over this wave's c-chunk
  {
    const float* Wm0 = Wmix + (size_t)(0*10 + e)*4096;
    const float* Wm1 = Wmix + (size_t)(1*10 + e)*4096;
    const float* Wm2 = Wmix + (size_t)(2*10 + e)*4096;
    float pax[9];
#pragma unroll
    for (int i=0;i<9;++i) pax[i] = 0.f;
    const int c0 = wid*16;
    for (int c=c0; c<c0+16; ++c){
      const float wv0 = Wm0[c*64+lane];
      const float wv1 = Wm1[c*64+lane];
      const float wv2 = Wm2[c*64+lane];
      pax[0] = fmaf(Ash[0][c], wv0, pax[0]);
#pragma unroll
      for (int m=0;m<3;++m) pax[1+m] = fmaf(Ash[1+m][c], wv1, pax[1+m]);
#pragma unroll
      for (int m=0;m<5;++m) pax[4+m] = fmaf(Ash[4+m][c], wv2, pax[4+m]);
    }
#pragma unroll
    for (int i=0;i<9;++i) Pt[wid][i][lane] = pax[i];
  }
  __syncthreads();
  // phase 4: wave 0 reduces ax, does symmetric contraction, writes Bsh
  if (wid == 0){
    float ax[9];
#pragma unroll
    for (int i=0;i<9;++i)
      ax[i] = (Pt[0][i][lane]+Pt[1][i][lane]+Pt[2][i][lane]+Pt[3][i][lane])
              * 0.0039528470752104741f;   // (1/AVG_NEIGH)*MIX_NORM
    const float* amix0 = ax;
    const float* amix1 = ax+1;
    const float* amix2 = ax+4;
    float w2n[5], w3n[5];
#pragma unroll
    for (int p=0;p<5;++p){
      w2n[p] = w2[(size_t)(e*5+p)*64 + lane];
      w3n[p] = w3[(size_t)(e*5+p)*64 + lane];
    }
    float t20[1] = {0.f}, t21[3] = {0.f,0.f,0.f};
    sc_accum<0,0,0>(amix0, amix0, w2n[0], t20);
    sc_accum<1,1,0>(amix1, amix1, w2n[1], t20);
    sc_accum<2,2,0>(amix2, amix2, w2n[2], t20);
    sc_accum<0,1,1>(amix0, amix1, w2n[3], t21);
    sc_accum<1,2,1>(amix1, amix2, w2n[4], t21);
    float t30[1] = {0.f}, t31[3] = {0.f,0.f,0.f};
    sc_accum<0,0,0>(t20, amix0, w3n[0], t30);
    sc_accum<1,1,0>(t21, amix1, w3n[1], t30);
    sc_accum<0,1,1>(t20, amix1, w3n[2], t31);
    sc_accum<1,0,1>(t21, amix0, w3n[3], t31);
    sc_accum<1,2,1>(t21, amix2, w3n[4], t31);
    const float w1_0 = w1[(size_t)(e*2+0)*64 + lane];
    const float w1_1 = w1[(size_t)(e*2+1)*64 + lane];
    Bsh[0][lane] = fmaf(w1_0, amix0[0], t20[0] + t30[0]);
#pragma unroll
    for (int m=0;m<3;++m) Bsh[1+m][lane] = fmaf(w1_1, amix1[m], t21[m] + t31[m]);
  }
  __syncthreads();
  // phase 5: output GEMM, c-split
  {
    const float* hrow = h1 + (long)n*576;
    float po[4];
#pragma unroll
    for (int i=0;i<4;++i) po[i] = 0.f;
    const int c0 = wid*16;
    for (int c=c0; c<c0+16; ++c){
      const float wh0 = Woh[c*64+lane];
      const float wh1 = Woh[4096 + c*64+lane];
      const float wm0 = Wom[c*64+lane];
      const float wm1 = Wom[4096 + c*64+lane];
      po[0] = fmaf(hrow[c], wh0, po[0]);
      po[0] = fmaf(Bsh[0][c], wm0, po[0]);
#pragma unroll
      for (int m=0;m<3;++m){
        po[1+m] = fmaf(hrow[64+m*64+c], wh1, po[1+m]);
        po[1+m] = fmaf(Bsh[1+m][c], wm1, po[1+m]);
      }
    }
#pragma unroll
    for (int i=0;i<4;++i) Pt[wid][i][lane] = po[i];
  }
  __syncthreads();
  // phase 6: reduce + write (4*64 = 256 entries, one per thread)
  {
    const int i = threadIdx.x >> 6, c = threadIdx.x & 63;
    out[(long)n*256 + i*64 + c] =
      (Pt[0][i][c]+Pt[1][i][c]+Pt[2][i][c]+Pt[3][i][c])*0.125f;
  }
}

// ---------------- launch ----------------
extern "C" void kernel_launch(void* const* d_in, const int* in_sizes, int n_in,
                              void* d_out, int out_size, void* d_ws, size_t ws_size,
                              hipStream_t stream){
  const int*   sender   = (const int*)  d_in[0];
  const int*   receiver = (const int*)  d_in[1];
  const int*   indices  = (const int*)  d_in[2];
  const float* node_feat= (const float*)d_in[4];
  const float* ele      = (const float*)d_in[5];
  const float* sph      = (const float*)d_in[6];
  const float* W_lin    = (const float*)d_in[7];
  const float* W0 = (const float*)d_in[8],  *b0 = (const float*)d_in[9];
  const float* W1 = (const float*)d_in[10], *b1 = (const float*)d_in[11];
  const float* W2 = (const float*)d_in[12], *b2 = (const float*)d_in[13];
  const float* W3 = (const float*)d_in[14], *b3 = (const float*)d_in[15];
  const float* Wmix = (const float*)d_in[16];
  const float* w1 = (const float*)d_in[17];
  const float* w2 = (const float*)d_in[18];
  const float* w3 = (const float*)d_in[19];
  const float* Wom = (const float*)d_in[20];
  const float* Woh = (const float*)d_in[21];
  float* out = (float*)d_out;

  char* ws = (char*)d_ws;
  const size_t OFF_H1P  = 0;
  const size_t OFF_HMLP = OFF_H1P  + (size_t)NNODES*576*4;
  const size_t OFF_MSG  = OFF_HMLP + (size_t)NEDGES*32*4;
  const size_t OFF_DEG  = OFF_MSG  + (size_t)NEDGES*576*2;
  const size_t OFF_ROW  = OFF_DEG  + 40960;
  const size_t OFF_CUR  = OFF_ROW  + 40960;
  const size_t OFF_EIDX = OFF_CUR  + 40960;

  float* h1p  = (float*)(ws + OFF_H1P);
  float* hmlp = (float*)(ws + OFF_HMLP);
  unsigned short* msg16 = (unsigned short*)(ws + OFF_MSG);
  int* deg    = (int*)(ws + OFF_DEG);
  int* rowptr = (int*)(ws + OFF_ROW);
  int* cursor = (int*)(ws + OFF_CUR);
  int* eidx   = (int*)(ws + OFF_EIDX);

  k_lin4<<<NNODES, 256, 0, stream>>>(node_feat, W_lin, h1p, deg);
  k_mlp<<<(NEDGES+255)/256, 256, 0, stream>>>(ele, W0,b0,W1,b1,W2,b2, hmlp);
  k_hist<<<(NEDGES+255)/256, 256, 0, stream>>>(receiver, deg);
  k_scan<<<1, 256, 0, stream>>>(deg, rowptr, cursor);
  k_fill<<<(NEDGES+255)/256, 256, 0, stream>>>(receiver, cursor, eidx);
  k_edge_g<0><<<NEDGES/16, 256, 0, stream>>>(sender, hmlp, sph, h1p, W3, b3, msg16);
  k_edge_g<1><<<NEDGES/16, 256, 0, stream>>>(sender, hmlp, sph, h1p, W3, b3, msg16);
  k_edge_g<2><<<NEDGES/16, 256, 0, stream>>>(sender, hmlp, sph, h1p, W3, b3, msg16);
  k_node4<<<NNODES, 256, 0, stream>>>(indices, node_feat, rowptr, eidx, msg16,
                                      Wmix, w1, w2, w3, Wom, Woh, out);
}

// Round 8
// 266.814 us; speedup vs baseline: 1.2700x; 1.2700x over previous
//
#include <hip/hip_runtime.h>
#include <math.h>

#define NNODES 10000
#define NEDGES 100000

// ---------------- compile-time Clebsch-Gordan (port of reference) ----------------
struct Cplx { double re, im; };

constexpr double cfact(int n){ double r=1.0; for(int i=2;i<=n;++i) r*=i; return r; }

constexpr double csqrt_(double x){
  if (x<=0.0) return 0.0;
  double g = x<1.0 ? 1.0 : x;
  for (int it=0; it<64; ++it){ double ng = 0.5*(g + x/g); if (ng==g) break; g = ng; }
  return g;
}

constexpr double cg_coeff(int j1,int m1,int j2,int m2,int j3,int m3){
  if (m1+m2!=m3) return 0.0;
  int lo = j1>j2 ? j1-j2 : j2-j1;
  if (j3<lo || j3>j1+j2) return 0.0;
  if (m1<-j1||m1>j1||m2<-j2||m2>j2||m3<-j3||m3>j3) return 0.0;
  double pre = csqrt_((2.0*j3+1.0)*cfact(j1+j2-j3)*cfact(j1-j2+j3)*cfact(-j1+j2+j3)/cfact(j1+j2+j3+1));
  pre *= csqrt_(cfact(j1+m1)*cfact(j1-m1)*cfact(j2+m2)*cfact(j2-m2)*cfact(j3+m3)*cfact(j3-m3));
  double s = 0.0;
  for (int k=0;k<=j1+j2+j3;++k){
    int d0=j1+j2-j3-k, d1=j1-m1-k, d2=j2+m2-k, d3=j3-j2+m1+k, d4=j3-j1-m2+k;
    if (d0<0||d1<0||d2<0||d3<0||d4<0) continue;
    double term = 1.0/(cfact(k)*cfact(d0)*cfact(d1)*cfact(d2)*cfact(d3)*cfact(d4));
    s += (k&1) ? -term : term;
  }
  return pre*s;
}

constexpr Cplx uent(int l,int a,int i){
  const double s = 0.70710678118654752440;
  int ma = a - l;
  if (ma==0) { if (i==l) return Cplx{1.0,0.0}; return Cplx{0.0,0.0}; }
  if (ma>0){
    int m = ma; double sg = (m&1) ? -1.0 : 1.0;
    if (i==l+m) return Cplx{sg*s, 0.0};
    if (i==l-m) return Cplx{s, 0.0};
    return Cplx{0.0,0.0};
  }
  int m = -ma; double sg = (m&1) ? -1.0 : 1.0;
  if (i==l+m) return Cplx{0.0, -sg*s};
  if (i==l-m) return Cplx{0.0, s};
  return Cplx{0.0,0.0};
}

constexpr double real_cg_entry(int l1,int l2,int l3,int a,int b,int c){
  double acc = 0.0;
  int ii0 = a, ii1 = 2*l1-a;
  int jj0 = b, jj1 = 2*l2-b;
  for (int x=0;x<2;++x){
    int i = (x==0)? ii0 : ii1;
    if (x==1 && ii1==ii0) break;
    Cplx u1 = uent(l1,a,i); if (u1.re==0.0 && u1.im==0.0) continue;
    for (int y=0;y<2;++y){
      int j = (y==0)? jj0 : jj1;
      if (y==1 && jj1==jj0) break;
      Cplx u2 = uent(l2,b,j); if (u2.re==0.0 && u2.im==0.0) continue;
      int k = (i-l1)+(j-l2)+l3;
      if (k<0 || k>2*l3) continue;
      Cplx u3 = uent(l3,c,k); if (u3.re==0.0 && u3.im==0.0) continue;
      double cg = cg_coeff(l1,i-l1,l2,j-l2,l3,k-l3);
      if (cg==0.0) continue;
      double pr = u1.re*u2.re - u1.im*u2.im;
      double pi = u1.re*u2.im + u1.im*u2.re;
      acc += (pr*u3.re + pi*u3.im) * cg;
    }
  }
  return acc;
}

struct CGT { float v[5][5][5]; };
constexpr CGT make_cg(int l1,int l2,int l3){
  CGT t{};
  for (int a=0;a<2*l1+1;++a)
    for (int b=0;b<2*l2+1;++b)
      for (int c=0;c<2*l3+1;++c)
        t.v[a][b][c] = (float)real_cg_entry(l1,l2,l3,a,b,c);
  return t;
}

// ---------------- device helpers ----------------
__device__ __forceinline__ float silu_(float x){ return x / (1.0f + __expf(-x)); }

union H16 { _Float16 h; unsigned short u; };
__device__ __forceinline__ unsigned short f2h(float x){ H16 c; c.h = (_Float16)x; return c.u; }
__device__ __forceinline__ float h2f(unsigned short u){ H16 c; c.u = u; return (float)c.h; }

template<int L1,int L2,int L3>
__device__ __forceinline__ void tp_accum(const float* sp, const float* g, float rl, float* msg){
  constexpr CGT T = make_cg(L1,L2,L3);
  constexpr int NA = 2*L1+1, NB = 2*L2+1, ND = 2*L3+1;
  float t[ND];
#pragma unroll
  for (int d=0; d<ND; ++d) t[d] = 0.f;
#pragma unroll
  for (int b=0;b<NB;++b){
#pragma unroll
    for (int d=0; d<ND; ++d){
      float u = 0.f; bool any = false;
#pragma unroll
      for (int a=0;a<NA;++a){
        const float cg = T.v[a][b][d];
        if (cg != 0.f){ u = fmaf(cg, sp[a], u); any = true; }
      }
      if (any) t[d] = fmaf(u, g[b], t[d]);
    }
  }
#pragma unroll
  for (int d=0;d<ND;++d) msg[d] = fmaf(rl, t[d], msg[d]);
}

template<int L1,int L2,int L3>
__device__ __forceinline__ void sc_accum(const float* X, const float* Y, float w, float* out){
  constexpr CGT T = make_cg(L1,L2,L3);
  constexpr int NA = 2*L1+1, NB = 2*L2+1, ND = 2*L3+1;
#pragma unroll
  for (int d=0;d<ND;++d){
    float s = 0.f;
#pragma unroll
    for (int a=0;a<NA;++a){
#pragma unroll
      for (int b=0;b<NB;++b){
        const float cg = T.v[a][b][d];
        if (cg != 0.f) s = fmaf(cg*X[a], Y[b], s);
      }
    }
    out[d] = fmaf(w, s, out[d]);
  }
}

// ---------------- kernel 1: h1p = per-irrep h1 @ W_lin_in * 1/sqrt(K); zero deg ----------------
__global__ void __launch_bounds__(64) k_lin_in(const float* __restrict__ h1,
                                               const float* __restrict__ W,
                                               float* __restrict__ h1p,
                                               int* __restrict__ deg){
  const int n = blockIdx.x;
  const int d = threadIdx.x;
  if (d == 0) deg[n] = 0;
  const float* row = h1 + (long)n*576;
  float acc[9];
#pragma unroll
  for (int i=0;i<9;++i) acc[i] = 0.f;
  for (int c=0;c<64;++c){
    const float w0 = W[c*64 + d];
    const float w1 = W[4096 + c*64 + d];
    const float w2 = W[8192 + c*64 + d];
    acc[0] = fmaf(row[c], w0, acc[0]);
#pragma unroll
    for (int m=0;m<3;++m) acc[1+m] = fmaf(row[64+m*64+c], w1, acc[1+m]);
#pragma unroll
    for (int m=0;m<5;++m) acc[4+m] = fmaf(row[256+m*64+c], w2, acc[4+m]);
  }
  float* o = h1p + (long)n*576;
  o[d] = acc[0]*0.125f;
#pragma unroll
  for (int m=0;m<3;++m) o[64+m*64+d] = acc[1+m]*0.125f;
#pragma unroll
  for (int m=0;m<5;++m) o[256+m*64+d] = acc[4+m]*0.125f;
}

// ---------------- kernel 1b: radial MLP hidden layers, lane = edge ----------------
__global__ void __launch_bounds__(256) k_mlp(const float* __restrict__ ele,
                                             const float* __restrict__ W0, const float* __restrict__ b0,
                                             const float* __restrict__ W1, const float* __restrict__ b1,
                                             const float* __restrict__ W2, const float* __restrict__ b2,
                                             float* __restrict__ hmlp){
  const int e = blockIdx.x*256 + threadIdx.x;
  if (e >= NEDGES) return;
  float x[8];
#pragma unroll
  for (int i=0;i<8;++i) x[i] = ele[(long)e*8 + i];
  float h[32];
#pragma unroll
  for (int d=0;d<32;++d){
    float acc = b0[d];
#pragma unroll
    for (int i=0;i<8;++i) acc = fmaf(x[i], W0[i*32+d], acc);
    h[d] = silu_(acc);
  }
#pragma unroll
  for (int L=0; L<2; ++L){
    const float* Wl = L ? W2 : W1;
    const float* bl = L ? b2 : b1;
    float acc[32];
#pragma unroll
    for (int d=0;d<32;++d) acc[d] = bl[d];
    for (int j=0;j<32;++j){
      const float hj = h[j];
#pragma unroll
      for (int d=0;d<32;++d) acc[d] = fmaf(hj, Wl[j*32+d], acc[d]);
    }
#pragma unroll
    for (int d=0;d<32;++d) h[d] += silu_(acc[d]);
  }
  float* o = hmlp + (long)e*32;
#pragma unroll
  for (int d=0;d<32;++d) o[d] = h[d];
}

// ---------------- CSR build kernels ----------------
__global__ void __launch_bounds__(256) k_hist(const int* __restrict__ receiver, int* __restrict__ deg){
  const int e = blockIdx.x*256 + threadIdx.x;
  if (e < NEDGES) atomicAdd(&deg[receiver[e]], 1);
}

__global__ void __launch_bounds__(256) k_scan(const int* __restrict__ deg,
                                              int* __restrict__ rowptr,
                                              int* __restrict__ cursor){
  __shared__ int sums[256];
  const int t = threadIdx.x;
  const int CH = 40;
  const int base = t*CH;
  int s = 0;
  for (int i=0;i<CH;++i){ int idx = base+i; if (idx < NNODES) s += deg[idx]; }
  sums[t] = s; __syncthreads();
  for (int off=1; off<256; off<<=1){
    int v = (t>=off) ? sums[t-off] : 0;
    __syncthreads();
    sums[t] += v;
    __syncthreads();
  }
  int run = (t==0) ? 0 : sums[t-1];
  for (int i=0;i<CH;++i){
    int idx = base+i;
    if (idx < NNODES){ rowptr[idx] = run; cursor[idx] = run; run += deg[idx]; }
  }
  if (t==255) rowptr[NNODES] = sums[255];
}

__global__ void __launch_bounds__(256) k_fill(const int* __restrict__ receiver,
                                              int* __restrict__ cursor,
                                              int* __restrict__ eidx){
  const int e = blockIdx.x*256 + threadIdx.x;
  if (e < NEDGES){
    int pos = atomicAdd(&cursor[receiver[e]], 1);
    eidx[pos] = e;
  }
}

// ---------------- kernel 2: single edge kernel, all 11 paths, EPW=8 ----------------
// launch_bounds(256,2): VGPR cap 256 fits the full live set (rl 88 + g 72 + w3v 44
// + addressing ~ 230) with ZERO spill. 2 waves/SIMD is enough: the kernel is
// VALU-dense (2816 rl-fma + ~900 TP-fma per wave vs ~420 loads).
__global__ void __launch_bounds__(256, 2) k_edge_all(const int* __restrict__ sender,
                                             const float* __restrict__ hmlp,
                                             const float* __restrict__ sph,
                                             const float* __restrict__ h1p,
                                             const float* __restrict__ W3, const float* __restrict__ b3,
                                             unsigned short* __restrict__ msg16){
  __shared__ float sps[4][72];
  const int wid  = threadIdx.x >> 6;
  const int lane = threadIdx.x & 63;
  const int ubase = __builtin_amdgcn_readfirstlane((blockIdx.x*4 + wid) * 8);

  // stage sph[ubase..ubase+8)[9] into LDS
  sps[wid][lane] = sph[(long)ubase*9 + lane];
  if (lane < 8) sps[wid][64+lane] = sph[(long)ubase*9 + 64 + lane];

  int sidx[8];
#pragma unroll
  for (int e=0;e<8;++e) sidx[e] = sender[ubase+e];

  // gather sender features ONCE; force issue here (latency hidden by rl GEMM)
  float g[8][9];
#pragma unroll
  for (int e=0;e<8;++e){
    const float* hp = h1p + (long)sidx[e]*576;
#pragma unroll
    for (int i=0;i<9;++i) g[e][i] = hp[i*64+lane];
  }
#pragma unroll
  for (int e=0;e<8;++e)
#pragma unroll
    for (int i=0;i<9;++i) asm volatile("" : "+v"(g[e][i]));

  const float* hu = hmlp + (long)ubase*32;   // wave-uniform -> s_load

  // rl GEMM: rl[p][e] = b3 + sum_j h[e][j]*W3[j][p*64+lane]
  float rl[11][8];
#pragma unroll
  for (int p=0;p<11;++p){
    const float bb = b3[p*64+lane];
#pragma unroll
    for (int e=0;e<8;++e) rl[p][e] = bb;
  }
  for (int jb=0;jb<32;jb+=4){
    float w3v[4][11];
#pragma unroll
    for (int jj=0;jj<4;++jj)
#pragma unroll
      for (int p=0;p<11;++p)
        w3v[jj][p] = W3[(jb+jj)*704 + p*64 + lane];
#pragma unroll
    for (int e=0;e<8;++e){
#pragma unroll
      for (int jj=0;jj<4;++jj){
        const float hj = hu[e*32 + jb + jj];
#pragma unroll
        for (int p=0;p<11;++p) rl[p][e] = fmaf(hj, w3v[jj][p], rl[p][e]);
      }
    }
  }

  // TP + f16 message store per edge
#pragma unroll
  for (int e=0;e<8;++e){
    const float* sp = &sps[wid][e*9];
    const size_t mb = (size_t)(ubase+e)*576;
    float m0[1] = {0.f};
    float m1[3] = {0.f,0.f,0.f};
    float m2[5] = {0.f,0.f,0.f,0.f,0.f};
    tp_accum<0,0,0>(sp+0, &g[e][0], rl[0][e],  m0);
    tp_accum<0,1,1>(sp+0, &g[e][1], rl[1][e],  m1);
    tp_accum<0,2,2>(sp+0, &g[e][4], rl[2][e],  m2);
    tp_accum<1,0,1>(sp+1, &g[e][0], rl[3][e],  m1);
    tp_accum<1,1,0>(sp+1, &g[e][1], rl[4][e],  m0);
    tp_accum<1,1,2>(sp+1, &g[e][1], rl[5][e],  m2);
    tp_accum<1,2,1>(sp+1, &g[e][4], rl[6][e],  m1);
    tp_accum<2,0,2>(sp+4, &g[e][0], rl[7][e],  m2);
    tp_accum<2,1,1>(sp+4, &g[e][1], rl[8][e],  m1);
    tp_accum<2,2,0>(sp+4, &g[e][4], rl[9][e],  m0);
    tp_accum<2,2,2>(sp+4, &g[e][4], rl[10][e], m2);
    msg16[mb + lane] = f2h(m0[0]);
#pragma unroll
    for (int m=0;m<3;++m) msg16[mb + (1+m)*64 + lane] = f2h(m1[m]);
#pragma unroll
    for (int m=0;m<5;++m) msg16[mb + (4+m)*64 + lane] = f2h(m2[m]);
  }
}

// ---------------- kernel 3: node kernel, ONE WAVE per node, zero barriers ----------------
// Key: Amix's output index d IS the channel the contraction consumes, so after the
// LDS-broadcast Amix everything stays lane-local. Per-wave LDS regions; waves in a
// block are independent (4 nodes/block); within-wave LDS RAW needs only lgkmcnt.
__global__ void __launch_bounds__(256) k_node_w(const int* __restrict__ indices,
                                             const float* __restrict__ h1,
                                             const int* __restrict__ rowptr,
                                             const int* __restrict__ eidx,
                                             const unsigned short* __restrict__ msg16,
                                             const float* __restrict__ Wmix,
                                             const float* __restrict__ w1,
                                             const float* __restrict__ w2,
                                             const float* __restrict__ w3,
                                             const float* __restrict__ Wom,
                                             const float* __restrict__ Woh,
                                             float* __restrict__ out){
  __shared__ float S[4][9][64];
  __shared__ float Bb[4][4][64];
  const int wid  = threadIdx.x >> 6;
  const int lane = threadIdx.x & 63;
  const int n = blockIdx.x*4 + wid;
  const int e = __builtin_amdgcn_readfirstlane(indices[n]);

  // phase 1: gather-sum incoming messages (lane = channel c) -> LDS
  {
    const int start = rowptr[n], end = rowptr[n+1];
    float A[9];
#pragma unroll
    for (int i=0;i<9;++i) A[i] = 0.f;
    for (int q=start; q<end; ++q){
      const int ed = eidx[q];
      const unsigned short* mp = msg16 + (size_t)ed*576;
#pragma unroll
      for (int i=0;i<9;++i) A[i] += h2f(mp[i*64+lane]);
    }
#pragma unroll
    for (int i=0;i<9;++i) S[wid][i][lane] = A[i];
  }

  // phase 2: Amix (lane = output channel d), LDS broadcast reads of S
  float ax[9];
#pragma unroll
  for (int i=0;i<9;++i) ax[i] = 0.f;
  {
    const float* Wm0 = Wmix + (size_t)(0*10 + e)*4096;
    const float* Wm1 = Wmix + (size_t)(1*10 + e)*4096;
    const float* Wm2 = Wmix + (size_t)(2*10 + e)*4096;
    for (int c=0;c<64;++c){
      const float wv0 = Wm0[c*64+lane];
      const float wv1 = Wm1[c*64+lane];
      const float wv2 = Wm2[c*64+lane];
      ax[0] = fmaf(S[wid][0][c], wv0, ax[0]);
#pragma unroll
      for (int m=0;m<3;++m) ax[1+m] = fmaf(S[wid][1+m][c], wv1, ax[1+m]);
#pragma unroll
      for (int m=0;m<5;++m) ax[4+m] = fmaf(S[wid][4+m][c], wv2, ax[4+m]);
    }
  }
#pragma unroll
  for (int i=0;i<9;++i) ax[i] *= 0.0039528470752104741f;  // (1/AVG_NEIGH)*MIX_NORM

  // phase 3: symmetric contraction, fully lane-local (lane = channel d)
  const float* amix0 = ax;
  const float* amix1 = ax+1;
  const float* amix2 = ax+4;
  float w2n[5], w3n[5];
#pragma unroll
  for (int p=0;p<5;++p){
    w2n[p] = w2[(size_t)(e*5+p)*64 + lane];
    w3n[p] = w3[(size_t)(e*5+p)*64 + lane];
  }
  float t20[1] = {0.f}, t21[3] = {0.f,0.f,0.f};
  sc_accum<0,0,0>(amix0, amix0, w2n[0], t20);
  sc_accum<1,1,0>(amix1, amix1, w2n[1], t20);
  sc_accum<2,2,0>(amix2, amix2, w2n[2], t20);
  sc_accum<0,1,1>(amix0, amix1, w2n[3], t21);
  sc_accum<1,2,1>(amix1, amix2, w2n[4], t21);
  float t30[1] = {0.f}, t31[3] = {0.f,0.f,0.f};
  sc_accum<0,0,0>(t20, amix0, w3n[0], t30);
  sc_accum<1,1,0>(t21, amix1, w3n[1], t30);
  sc_accum<0,1,1>(t20, amix1, w3n[2], t31);
  sc_accum<1,0,1>(t21, amix0, w3n[3], t31);
  sc_accum<1,2,1>(t21, amix2, w3n[4], t31);

  const float w1_0 = w1[(size_t)(e*2+0)*64 + lane];
  const float w1_1 = w1[(size_t)(e*2+1)*64 + lane];
  Bb[wid][0][lane] = fmaf(w1_0, amix0[0], t20[0] + t30[0]);
#pragma unroll
  for (int m=0;m<3;++m) Bb[wid][1+m][lane] = fmaf(w1_1, amix1[m], t21[m] + t31[m]);

  // phase 4: stage h1 row into S (overwrite; same wave finished reading it)
  {
    const float* hrow = h1 + (long)n*576;
#pragma unroll
    for (int r=0;r<9;++r) S[wid][r][lane] = hrow[r*64 + lane];
  }

  // phase 5: output linears (lane = d), LDS broadcast reads of S and Bb
  float o[4];
#pragma unroll
  for (int i=0;i<4;++i) o[i] = 0.f;
  for (int c=0;c<64;++c){
    const float wh0 = Woh[c*64+lane];
    const float wh1 = Woh[4096 + c*64+lane];
    const float wm0 = Wom[c*64+lane];
    const float wm1 = Wom[4096 + c*64+lane];
    o[0] = fmaf(S[wid][0][c], wh0, o[0]);
    o[0] = fmaf(Bb[wid][0][c], wm0, o[0]);
#pragma unroll
    for (int m=0;m<3;++m){
      o[1+m] = fmaf(S[wid][1+m][c], wh1, o[1+m]);
      o[1+m] = fmaf(Bb[wid][1+m][c], wm1, o[1+m]);
    }
  }
  float* orow = out + (long)n*256;
  orow[lane] = o[0]*0.125f;
#pragma unroll
  for (int m=0;m<3;++m) orow[64+m*64+lane] = o[1+m]*0.125f;
}

// ---------------- launch ----------------
extern "C" void kernel_launch(void* const* d_in, const int* in_sizes, int n_in,
                              void* d_out, int out_size, void* d_ws, size_t ws_size,
                              hipStream_t stream){
  const int*   sender   = (const int*)  d_in[0];
  const int*   receiver = (const int*)  d_in[1];
  const int*   indices  = (const int*)  d_in[2];
  const float* node_feat= (const float*)d_in[4];
  const float* ele      = (const float*)d_in[5];
  const float* sph      = (const float*)d_in[6];
  const float* W_lin    = (const float*)d_in[7];
  const float* W0 = (const float*)d_in[8],  *b0 = (const float*)d_in[9];
  const float* W1 = (const float*)d_in[10], *b1 = (const float*)d_in[11];
  const float* W2 = (const float*)d_in[12], *b2 = (const float*)d_in[13];
  const float* W3 = (const float*)d_in[14], *b3 = (const float*)d_in[15];
  const float* Wmix = (const float*)d_in[16];
  const float* w1 = (const float*)d_in[17];
  const float* w2 = (const float*)d_in[18];
  const float* w3 = (const float*)d_in[19];
  const float* Wom = (const float*)d_in[20];
  const float* Woh = (const float*)d_in[21];
  float* out = (float*)d_out;

  char* ws = (char*)d_ws;
  const size_t OFF_H1P  = 0;
  const size_t OFF_HMLP = OFF_H1P  + (size_t)NNODES*576*4;
  const size_t OFF_MSG  = OFF_HMLP + (size_t)NEDGES*32*4;
  const size_t OFF_DEG  = OFF_MSG  + (size_t)NEDGES*576*2;
  const size_t OFF_ROW  = OFF_DEG  + 40960;
  const size_t OFF_CUR  = OFF_ROW  + 40960;
  const size_t OFF_EIDX = OFF_CUR  + 40960;

  float* h1p  = (float*)(ws + OFF_H1P);
  float* hmlp = (float*)(ws + OFF_HMLP);
  unsigned short* msg16 = (unsigned short*)(ws + OFF_MSG);
  int* deg    = (int*)(ws + OFF_DEG);
  int* rowptr = (int*)(ws + OFF_ROW);
  int* cursor = (int*)(ws + OFF_CUR);
  int* eidx   = (int*)(ws + OFF_EIDX);

  k_lin_in<<<NNODES, 64, 0, stream>>>(node_feat, W_lin, h1p, deg);
  k_mlp<<<(NEDGES+255)/256, 256, 0, stream>>>(ele, W0,b0,W1,b1,W2,b2, hmlp);
  k_hist<<<(NEDGES+255)/256, 256, 0, stream>>>(receiver, deg);
  k_scan<<<1, 256, 0, stream>>>(deg, rowptr, cursor);
  k_fill<<<(NEDGES+255)/256, 256, 0, stream>>>(receiver, cursor, eidx);
  k_edge_all<<<NEDGES/32, 256, 0, stream>>>(sender, hmlp, sph, h1p, W3, b3, msg16);
  k_node_w<<<NNODES/4, 256, 0, stream>>>(indices, node_feat, rowptr, eidx, msg16,
                                         Wmix, w1, w2, w3, Wom, Woh, out);
}